// Round 8
// baseline (26057.437 us; speedup 1.0000x reference)
//
#include <hip/hip_runtime.h>

constexpr int NB = 32;    // batch
constexpr int NT = 128;   // time
constexpr int NE = 256;   // embed
constexpr int NH = 256;   // hidden
constexpr int NC = 16;    // classes

typedef _Float16 f16;
typedef f16 f16x2 __attribute__((ext_vector_type(2)));
typedef f16 f16x8 __attribute__((ext_vector_type(8)));

__device__ __forceinline__ float sigmoidf_(float x) {
    return 1.f / (1.f + __expf(-x));
}
__device__ __forceinline__ float tanhf_(float x) {
    x = fminf(fmaxf(x, -15.f), 15.f);
    float e = __expf(-2.f * x);
    return (1.f - e) / (1.f + e);
}
__device__ __forceinline__ float dot4_(float4 a, float4 b) {
    return a.x * b.x + a.y * b.y + a.z * b.z + a.w * b.w;
}
#if __has_builtin(__builtin_amdgcn_fdot2)
__device__ __forceinline__ float fdot2_(f16x2 a, f16x2 b, float c) {
    return __builtin_amdgcn_fdot2(a, b, c, false);
}
#else
__device__ __forceinline__ float fdot2_(f16x2 a, f16x2 b, float c) {
    return (float)a[0] * (float)b[0] + (float)a[1] * (float)b[1] + c;
}
#endif
#define PAIR(v, k) __builtin_shufflevector((v), (v), (k), (k) + 1)

// ---- fp8 e4m3 path selection (pack encode and chain decode MUST match) ----
#if __has_builtin(__builtin_amdgcn_cvt_pk_f16_fp8)
#define FP8_HW 1
__device__ __forceinline__ void dec4_(unsigned int d, f16x2& a, f16x2& b) {
    a = __builtin_bit_cast(f16x2, __builtin_amdgcn_cvt_pk_f16_fp8((short)(d & 0xffffu)));
    b = __builtin_bit_cast(f16x2, __builtin_amdgcn_cvt_pk_f16_fp8((short)(d >> 16)));
}
#else
#define FP8_HW 0
// bytes packed (k0,k2,k1,k3): evens -> a=(k0,k1), odds -> b=(k2,k3).
// all stored values are e4m3 NORMAL (pack flushes denorms) -> exact bit decode.
__device__ __forceinline__ void dec4_(unsigned int d, f16x2& a, f16x2& b) {
    unsigned int ev = d & 0x00ff00ffu;
    unsigned int od = (d >> 8) & 0x00ff00ffu;
    unsigned int ea = (((ev & 0x007f007fu) << 7) + 0x20002000u) | ((ev & 0x00800080u) << 8);
    unsigned int eb = (((od & 0x007f007fu) << 7) + 0x20002000u) | ((od & 0x00800080u) << 8);
    a = __builtin_bit_cast(f16x2, ea);
    b = __builtin_bit_cast(f16x2, eb);
}
#endif

// encode w*64 as e4m3 (RNE), denorms flushed to smallest normal (2^-6)
__device__ __forceinline__ unsigned char enc8_(float w) {
    const float f = w * 64.f;
    const unsigned int b = __builtin_bit_cast(unsigned int, f);
    const unsigned int sgn = (b >> 24) & 0x80u;
    unsigned int mag = b & 0x7fffffffu;
    if (mag < 0x3c800000u) return (unsigned char)(sgn | 0x08u);
    if (mag > 0x43e00000u) mag = 0x43e00000u;
    unsigned int base = mag >> 20;
    const unsigned int rem = mag & 0xfffffu;
    base += (rem > 0x80000u) || (rem == 0x80000u && (base & 1u));
    if (base > 1086u) base = 1086u;
    return (unsigned char)(sgn | (base - 960u));
}

// ---------------- Prologue 1: xp[t][b][j] = x[b][t][:] . W_in[j][:] + b_in[j]
__global__ __launch_bounds__(256) void k_lin_in(
    const float* __restrict__ x, const float* __restrict__ W_in,
    const float* __restrict__ b_in, float* __restrict__ xp) {
    const int tb = blockIdx.x;           // t*NB + b
    const int t = tb >> 5, b = tb & 31;
    const int tid = threadIdx.x;
    __shared__ __align__(16) float xl[NE];
    xl[tid] = x[(b * NT + t) * NE + tid];
    __syncthreads();
    const float* __restrict__ wr = W_in + tid * NE;
    float acc = b_in[tid];
#pragma unroll 8
    for (int k = 0; k < NE; k += 4)
        acc += dot4_(*(const float4*)(wr + k), *(const float4*)(xl + k));
    xp[tb * NH + tid] = acc;
}

// ---------------- Prologue 2: xw = xp.Wih^T + bih ; uax = xp.Ua^T + ub
__global__ __launch_bounds__(256) void k_proj(
    const float* __restrict__ xp, const float* __restrict__ Wih,
    const float* __restrict__ bih, const float* __restrict__ Ua,
    const float* __restrict__ ub, float* __restrict__ xw,
    float* __restrict__ uax) {
    const int tb = blockIdx.x;
    const int tid = threadIdx.x;
    __shared__ __align__(16) float xl[NH];
    xl[tid] = xp[tb * NH + tid];
    __syncthreads();
    const float* __restrict__ wr = Wih + tid * NH;
    const float* __restrict__ wz = Wih + (NH + tid) * NH;
    const float* __restrict__ wn = Wih + (2 * NH + tid) * NH;
    const float* __restrict__ wu = Ua + tid * NH;
    float ar = bih[tid], az = bih[NH + tid], an = bih[2 * NH + tid], au = ub[tid];
#pragma unroll 4
    for (int k = 0; k < NH; k += 4) {
        float4 xv = *(const float4*)(xl + k);
        ar += dot4_(*(const float4*)(wr + k), xv);
        az += dot4_(*(const float4*)(wz + k), xv);
        an += dot4_(*(const float4*)(wn + k), xv);
        au += dot4_(*(const float4*)(wu + k), xv);
    }
    float* xwp = xw + tb * (3 * NH);
    xwp[tid] = ar;
    xwp[NH + tid] = az;
    xwp[2 * NH + tid] = an;
    uax[tb * NH + tid] = au;
}

// ---------------- Pack Whh/Wa to f16x8 [kc][row] so k_attn's loads coalesce.
__global__ __launch_bounds__(256) void k_pack(
    const float* __restrict__ Whh, const float* __restrict__ Wa,
    f16x8* __restrict__ Wpk, f16x8* __restrict__ Wak) {
    const int id = blockIdx.x * 256 + threadIdx.x;
    if (id < 32 * 768) {
        const int kc = id / 768, row = id % 768;
        const float* src = Whh + row * NH + kc * 8;
        f16x8 v;
#pragma unroll
        for (int m = 0; m < 8; ++m) v[m] = (f16)src[m];
        Wpk[id] = v;
    } else {
        const int id2 = id - 32 * 768;   // < 8192
        const int kc = id2 >> 8, row = id2 & 255;
        const float* src = Wa + row * NH + kc * 8;
        f16x8 v;
#pragma unroll
        for (int m = 0; m < 8; ++m) v[m] = (f16)src[m];
        Wak[id2] = v;
    }
}

// ---------------- Pack n-gate (full) and r-gate (upper k-half) to fp8 granules
// matching k_chain's LDS layout: 8-byte granule per (s, wv, lane).
__global__ __launch_bounds__(256) void k_pack8(
    const float* __restrict__ Whh, unsigned char* __restrict__ wsn,
    unsigned char* __restrict__ wsr) {
    const int id = blockIdx.x * 256 + threadIdx.x;   // < 12288
    const bool isN = id < 8192;
    const int g = isN ? id : id - 8192;
    const int s = g >> 9, wvl = g & 511;             // wvl = wv*64+lane = thread id
    const int j = wvl >> 1, c = wvl & 1;
    const int row = isN ? (2 * NH + j) : j;
    const int kbase = isN ? (c * 128 + s * 8) : (c * 128 + 64 + s * 8);
    const float* src = Whh + (size_t)row * NH + kbase;
    unsigned char out[8];
#pragma unroll
    for (int dw = 0; dw < 2; ++dw)
#pragma unroll
        for (int p = 0; p < 4; ++p) {
#if FP8_HW
            const int koff = p;
#else
            const int koff = (p == 1) ? 2 : (p == 2) ? 1 : p;   // (0,2,1,3)
#endif
            out[dw * 4 + p] = enc8_(src[dw * 4 + koff]);
        }
        unsigned char* dst = (isN ? wsn : wsr) + (size_t)g * 8;
#pragma unroll
    for (int m = 0; m < 8; ++m) dst[m] = out[m];
}

// ---------------- Phase 1: sequential carried-hidden chain. 1 WG / batch.
// 512 threads (cap 128 VGPR): j = tid>>1 (row), c = tid&1 (128-wide k-half).
// z fp16 in regs (64 VGPRs) + r-low-half fp16 in regs (32); n + r-high-half
// as fp8 e4m3 in LDS (96 KB, wave-contiguous granules). No spill by design:
// 384 KB/step of fp16 weights exceeds every CU storage combo, so 96 KB is fp8.
__global__ __launch_bounds__(512) void k_chain(
    const float* __restrict__ Whh, const float* __restrict__ bhh,
    const float* __restrict__ xw, const unsigned char* __restrict__ wsn,
    const unsigned char* __restrict__ wsr, float* __restrict__ Hc) {
    const int b = blockIdx.x;
    const int tid = threadIdx.x;
    const int j = tid >> 1, c = tid & 1;
    const int wv = tid >> 6, lane = tid & 63;

    __shared__ __align__(16) uint2 WnL[16 * 8 * 64];   // n fp8 [s][wv][lane], 64 KB
    __shared__ __align__(16) uint2 WrL[8 * 8 * 64];    // r-hi fp8, 32 KB
    __shared__ __align__(16) f16 hb[2][NH];

    // ---- stage fp8 weights (coalesced 8B copies)
    {
        const uint2* srcn = (const uint2*)wsn;
        const uint2* srcr = (const uint2*)wsr;
        for (int idx = tid; idx < 8192; idx += 512) WnL[idx] = srcn[idx];
        for (int idx = tid; idx < 4096; idx += 512) WrL[idx] = srcr[idx];
    }
    // ---- persist z (full k-half) + r (low 64) fp16 in regs
    f16x2 wz[64], wrA[32];
    {
        const float2* pz = (const float2*)(Whh + (size_t)(NH + j) * NH + c * 128);
        const float2* pr = (const float2*)(Whh + (size_t)j * NH + c * 128);
#pragma unroll
        for (int m = 0; m < 64; ++m) { float2 v = pz[m]; wz[m] = f16x2{(f16)v.x, (f16)v.y}; }
#pragma unroll
        for (int m = 0; m < 32; ++m) { float2 v = pr[m]; wrA[m] = f16x2{(f16)v.x, (f16)v.y}; }
    }
    const float bhr = bhh[j], bhz = bhh[NH + j], bhn = bhh[2 * NH + j];
    if (tid < NH) hb[0][tid] = (f16)0.f;
    float hprev = 0.f;
    int cur = 0;
    const float* __restrict__ xwB = xw + (size_t)b * 3 * NH;
    float xr = xwB[j], xz = xwB[NH + j], xn = xwB[2 * NH + j];
    __syncthreads();

    const uint2* __restrict__ wn8 = WnL + wv * 64 + lane;
    const uint2* __restrict__ wr8 = WrL + wv * 64 + lane;
    constexpr float S8 = 1.f / 64.f;

#pragma unroll 1
    for (int i = 0; i < NT; ++i) {
#pragma unroll 1
        for (int t = 0; t <= i; ++t) {
            const int tn = (t < i) ? t + 1 : 0;
            const float* __restrict__ xwn = xw + (size_t)(tn * NB + b) * (3 * NH);
            const float nxr = xwn[j], nxz = xwn[NH + j], nxn = xwn[2 * NH + j];

            const f16* hc = hb[cur] + c * 128;
            float arA = 0.f, arB = 0.f, az = 0.f, an = 0.f;
#pragma unroll
            for (int s = 0; s < 8; ++s) {           // k 0..63: r from regs
                const f16x8 hv = *(const f16x8*)(hc + s * 8);
                const uint2 nw = wn8[s * 512];
                f16x2 n0, n1, n2, n3;
                dec4_(nw.x, n0, n1);
                dec4_(nw.y, n2, n3);
                const f16x2 h0 = PAIR(hv, 0), h1 = PAIR(hv, 2),
                            h2 = PAIR(hv, 4), h3 = PAIR(hv, 6);
                arA = fdot2_(wrA[s * 4 + 0], h0, arA);
                arA = fdot2_(wrA[s * 4 + 1], h1, arA);
                arA = fdot2_(wrA[s * 4 + 2], h2, arA);
                arA = fdot2_(wrA[s * 4 + 3], h3, arA);
                az = fdot2_(wz[s * 4 + 0], h0, az);
                az = fdot2_(wz[s * 4 + 1], h1, az);
                az = fdot2_(wz[s * 4 + 2], h2, az);
                az = fdot2_(wz[s * 4 + 3], h3, az);
                an = fdot2_(n0, h0, an);
                an = fdot2_(n1, h1, an);
                an = fdot2_(n2, h2, an);
                an = fdot2_(n3, h3, an);
            }
#pragma unroll
            for (int s = 8; s < 16; ++s) {          // k 64..127: r from fp8 LDS
                const f16x8 hv = *(const f16x8*)(hc + s * 8);
                const uint2 nw = wn8[s * 512];
                const uint2 rw = wr8[(s - 8) * 512];
                f16x2 n0, n1, n2, n3, r0, r1, r2, r3;
                dec4_(nw.x, n0, n1);
                dec4_(nw.y, n2, n3);
                dec4_(rw.x, r0, r1);
                dec4_(rw.y, r2, r3);
                const f16x2 h0 = PAIR(hv, 0), h1 = PAIR(hv, 2),
                            h2 = PAIR(hv, 4), h3 = PAIR(hv, 6);
                arB = fdot2_(r0, h0, arB);
                arB = fdot2_(r1, h1, arB);
                arB = fdot2_(r2, h2, arB);
                arB = fdot2_(r3, h3, arB);
                az = fdot2_(wz[s * 4 + 0], h0, az);
                az = fdot2_(wz[s * 4 + 1], h1, az);
                az = fdot2_(wz[s * 4 + 2], h2, az);
                az = fdot2_(wz[s * 4 + 3], h3, az);
                an = fdot2_(n0, h0, an);
                an = fdot2_(n1, h1, an);
                an = fdot2_(n2, h2, an);
                an = fdot2_(n3, h3, an);
            }
            const float myar = arA + arB * S8;
            const float ar = myar + __shfl_xor(myar, 1);
            const float azf = az + __shfl_xor(az, 1);
            const float anp = an + __shfl_xor(an, 1);
            const float anf = anp * S8;
            const float r = sigmoidf_(xr + ar + bhr);
            const float z = sigmoidf_(xz + azf + bhz);
            const float n = tanhf_(xn + r * (anf + bhn));
            const float hnew = (1.f - z) * n + z * hprev;
            hprev = hnew;
            if (c == 0) {
                hb[cur ^ 1][j] = (f16)hnew;
                if (t == i) Hc[((size_t)i * NB + b) * NH + j] = hnew;
            }
            xr = nxr; xz = nxz; xn = nxn;
            cur ^= 1;
            __syncthreads();
        }
    }
}

// ---------------- Phase 2: lockstep re-run of all prefix chains + fused attention.
__global__ __launch_bounds__(512) void k_attn(
    const float* __restrict__ Hc, const float* __restrict__ xw,
    const float* __restrict__ uax, const float* __restrict__ xp,
    const f16x8* __restrict__ Wpk, const f16x8* __restrict__ Wak,
    const float* __restrict__ bhh, const float* __restrict__ ba,
    const float* __restrict__ va_w, const float* __restrict__ Wo,
    const float* __restrict__ bo, float* __restrict__ out) {
    const int b  = blockIdx.x >> 3;
    const int bk = blockIdx.x & 7;
    const int tid = threadIdx.x;
    const int col = tid >> 1, c = tid & 1;
    const int lane = tid & 63, wid = tid >> 6;

    __shared__ __align__(16) float S[16][NH];
    __shared__ __align__(16) f16 Sh[16][NH];
    __shared__ float red1[8][16];
    __shared__ float mL[16], lL[16], aL[16], eL[16];
    __shared__ float redH[8][256];

    const float bhr = bhh[col], bhz = bhh[NH + col], bhn = bhh[2 * NH + col];
    const float ba_j = ba[col], va_j = va_w[col];
    float ctx[16];
#pragma unroll
    for (int u = 0; u < 16; ++u) {
        const int ic = bk + 8 * u;
        const float hv = (ic == 0) ? 0.f : Hc[((size_t)(ic - 1) * NB + b) * NH + col];
        if (c == 0) { S[u][col] = hv; Sh[u][col] = (f16)hv; }
        ctx[u] = 0.f;
    }
    if (tid < 16) { mL[tid] = -1e30f; lL[tid] = 0.f; }
    __syncthreads();

    const int imax = bk + 8 * 15;
#pragma unroll 1
    for (int t = 0; t <= imax; ++t) {
        const size_t base = (size_t)(t * NB + b);
        const float xr = xw[base * 3 * NH + col];
        const float xz = xw[base * 3 * NH + NH + col];
        const float xn = xw[base * 3 * NH + 2 * NH + col];
        const float ux = uax[base * NH + col];
        const float xpt = xp[base * NH + col];

        float ar[16], az[16], an[16];
#pragma unroll
        for (int u = 0; u < 16; ++u) { ar[u] = 0.f; az[u] = 0.f; an[u] = 0.f; }
        {
            int kc = c;
            f16x8 wR = Wpk[kc * 768 + col];
            f16x8 wZ = Wpk[kc * 768 + 256 + col];
            f16x8 wN = Wpk[kc * 768 + 512 + col];
#pragma unroll 1
            for (int kk = 0; kk < 16; ++kk) {
                const int kcn = kc + 2;
                f16x8 nR, nZ, nN;
                if (kk < 15) {
                    nR = Wpk[kcn * 768 + col];
                    nZ = Wpk[kcn * 768 + 256 + col];
                    nN = Wpk[kcn * 768 + 512 + col];
                }
#pragma unroll
                for (int u = 0; u < 16; ++u) {
                    if (bk + 8 * u < t) continue;
                    const f16x8 hv = *(const f16x8*)&Sh[u][kc * 8];
                    const f16x2 h0 = PAIR(hv, 0), h1 = PAIR(hv, 2),
                                h2 = PAIR(hv, 4), h3 = PAIR(hv, 6);
                    ar[u] = fdot2_(PAIR(wR, 0), h0, ar[u]);
                    ar[u] = fdot2_(PAIR(wR, 2), h1, ar[u]);
                    ar[u] = fdot2_(PAIR(wR, 4), h2, ar[u]);
                    ar[u] = fdot2_(PAIR(wR, 6), h3, ar[u]);
                    az[u] = fdot2_(PAIR(wZ, 0), h0, az[u]);
                    az[u] = fdot2_(PAIR(wZ, 2), h1, az[u]);
                    az[u] = fdot2_(PAIR(wZ, 4), h2, az[u]);
                    az[u] = fdot2_(PAIR(wZ, 6), h3, az[u]);
                    an[u] = fdot2_(PAIR(wN, 0), h0, an[u]);
                    an[u] = fdot2_(PAIR(wN, 2), h1, an[u]);
                    an[u] = fdot2_(PAIR(wN, 4), h2, an[u]);
                    an[u] = fdot2_(PAIR(wN, 6), h3, an[u]);
                }
                wR = nR; wZ = nZ; wN = nN; kc = kcn;
            }
        }
        float hn[16];
#pragma unroll
        for (int u = 0; u < 16; ++u) {
            if (bk + 8 * u < t) continue;
            float arf = ar[u] + __shfl_xor(ar[u], 1);
            float azf = az[u] + __shfl_xor(az[u], 1);
            float anf = an[u] + __shfl_xor(an[u], 1);
            const float r = sigmoidf_(xr + arf + bhr);
            const float z = sigmoidf_(xz + azf + bhz);
            const float n = tanhf_(xn + r * (anf + bhn));
            hn[u] = (1.f - z) * n + z * S[u][col];
        }
        __syncthreads();
#pragma unroll
        for (int u = 0; u < 16; ++u) {
            if (bk + 8 * u < t) continue;
            if (c == 0) { S[u][col] = hn[u]; Sh[u][col] = (f16)hn[u]; }
        }
        __syncthreads();

        float sc[16];
#pragma unroll
        for (int u = 0; u < 16; ++u) sc[u] = 0.f;
        {
            int kc = c;
            f16x8 wA = Wak[kc * 256 + col];
#pragma unroll 1
            for (int kk = 0; kk < 16; ++kk) {
                const int kcn = kc + 2;
                f16x8 nA;
                if (kk < 15) nA = Wak[kcn * 256 + col];
#pragma unroll
                for (int u = 0; u < 16; ++u) {
                    if (bk + 8 * u < t) continue;
                    const f16x8 hv = *(const f16x8*)&Sh[u][kc * 8];
                    sc[u] = fdot2_(PAIR(wA, 0), PAIR(hv, 0), sc[u]);
                    sc[u] = fdot2_(PAIR(wA, 2), PAIR(hv, 2), sc[u]);
                    sc[u] = fdot2_(PAIR(wA, 4), PAIR(hv, 4), sc[u]);
                    sc[u] = fdot2_(PAIR(wA, 6), PAIR(hv, 6), sc[u]);
                }
                wA = nA; kc = kcn;
            }
        }
#pragma unroll
        for (int u = 0; u < 16; ++u) {
            if (bk + 8 * u < t) continue;
            const float sv = sc[u] + __shfl_xor(sc[u], 1);
            float p = (c == 0) ? va_j * tanhf_(sv + ba_j + ux) : 0.f;
#pragma unroll
            for (int off = 32; off; off >>= 1) p += __shfl_xor(p, off);
            if (lane == 0) red1[wid][u] = p;
        }
        __syncthreads();
        if (tid < 16 && bk + 8 * tid >= t) {
            float s = 0.f;
#pragma unroll
            for (int w = 0; w < 8; ++w) s += red1[w][tid];
            const float mo = mL[tid];
            const float mn = fmaxf(mo, s);
            const float e  = __expf(s - mn);
            const float al = __expf(mo - mn);
            lL[tid] = lL[tid] * al + e;
            mL[tid] = mn; aL[tid] = al; eL[tid] = e;
        }
        __syncthreads();
#pragma unroll
        for (int u = 0; u < 16; ++u) {
            if (bk + 8 * u < t) continue;
            ctx[u] = ctx[u] * aL[u] + eL[u] * xpt;
        }
    }

#pragma unroll 1
    for (int u = 0; u < 16; ++u) {
        const float hl = S[u][col];
        const float cx = ctx[u] / lL[u];
#pragma unroll
        for (int cls = 0; cls < NC; ++cls) {
            float p = Wo[cls * (2 * NH) + col] * hl + Wo[cls * (2 * NH) + NH + col] * cx;
            p = (c == 0) ? p : 0.f;
#pragma unroll
            for (int off = 32; off; off >>= 1) p += __shfl_xor(p, off);
            if (lane == 0) redH[wid][u * 16 + cls] = p;
        }
    }
    __syncthreads();
    if (tid < 256) {
        const int u = tid >> 4, cls = tid & 15;
        const int ic = bk + 8 * u;
        float lg = bo[cls];
#pragma unroll
        for (int w = 0; w < 8; ++w) lg += redH[w][tid];
        out[((size_t)b * NT + ic) * NC + cls] = sigmoidf_(lg);
    }
}

extern "C" void kernel_launch(void* const* d_in, const int* in_sizes, int n_in,
                              void* d_out, int out_size, void* d_ws, size_t ws_size,
                              hipStream_t stream) {
    (void)in_sizes; (void)n_in; (void)out_size; (void)ws_size;
    const float* x    = (const float*)d_in[0];
    const float* W_in = (const float*)d_in[1];
    const float* b_in = (const float*)d_in[2];
    const float* Wih  = (const float*)d_in[3];
    const float* bih  = (const float*)d_in[4];
    const float* Whh  = (const float*)d_in[5];
    const float* bhh  = (const float*)d_in[6];
    const float* Wa   = (const float*)d_in[7];
    const float* ba   = (const float*)d_in[8];
    const float* Ua   = (const float*)d_in[9];
    const float* ub   = (const float*)d_in[10];
    const float* va_w = (const float*)d_in[11];
    // d_in[12] = va_b: cancels in softmax
    const float* Wo   = (const float*)d_in[13];
    const float* bo   = (const float*)d_in[14];
    float* out = (float*)d_out;

    float* ws  = (float*)d_ws;
    float* xp  = ws;                                    // NT*NB*NH        (4 MB)
    float* xw  = xp  + (size_t)NT * NB * NH;            // NT*NB*3NH       (12.6 MB)
    float* uax = xw  + (size_t)NT * NB * 3 * NH;        // NT*NB*NH        (4 MB)
    float* Hc  = uax + (size_t)NT * NB * NH;            // NT*NB*NH        (4 MB)
    f16x8* Wpk = (f16x8*)(Hc + (size_t)NT * NB * NH);   // 32*768 f16x8    (384 KB)
    f16x8* Wak = Wpk + 32 * 768;                        // 32*256 f16x8    (128 KB)
    unsigned char* wsn = (unsigned char*)(Wak + 32 * 256);  // 64 KB fp8 n-gate
    unsigned char* wsr = wsn + 16 * 8 * 64 * 8;             // 32 KB fp8 r-hi

    hipLaunchKernelGGL(k_lin_in, dim3(NT * NB), dim3(256), 0, stream, x, W_in, b_in, xp);
    hipLaunchKernelGGL(k_proj,   dim3(NT * NB), dim3(256), 0, stream, xp, Wih, bih, Ua, ub, xw, uax);
    hipLaunchKernelGGL(k_pack,   dim3(128),     dim3(256), 0, stream, Whh, Wa, Wpk, Wak);
    hipLaunchKernelGGL(k_pack8,  dim3(48),      dim3(256), 0, stream, Whh, wsn, wsr);
    hipLaunchKernelGGL(k_chain,  dim3(NB),      dim3(512), 0, stream, Whh, bhh, xw, wsn, wsr, Hc);
    hipLaunchKernelGGL(k_attn,   dim3(NB * 8),  dim3(512), 0, stream,
                       Hc, xw, uax, xp, Wpk, Wak, bhh, ba, va_w, Wo, bo, out);
}

// Round 9
// 20033.734 us; speedup vs baseline: 1.3007x; 1.3007x over previous
//
#include <hip/hip_runtime.h>

constexpr int NB = 32;    // batch
constexpr int NT = 128;   // time
constexpr int NE = 256;   // embed
constexpr int NH = 256;   // hidden
constexpr int NC = 16;    // classes

typedef _Float16 f16;
typedef f16 f16x2 __attribute__((ext_vector_type(2)));
typedef f16 f16x8 __attribute__((ext_vector_type(8)));

__device__ __forceinline__ float sigmoidf_(float x) {
    return 1.f / (1.f + __expf(-x));
}
__device__ __forceinline__ float tanhf_(float x) {
    x = fminf(fmaxf(x, -15.f), 15.f);
    float e = __expf(-2.f * x);
    return (1.f - e) / (1.f + e);
}
__device__ __forceinline__ float dot4_(float4 a, float4 b) {
    return a.x * b.x + a.y * b.y + a.z * b.z + a.w * b.w;
}
#if __has_builtin(__builtin_amdgcn_fdot2)
__device__ __forceinline__ float fdot2_(f16x2 a, f16x2 b, float c) {
    return __builtin_amdgcn_fdot2(a, b, c, false);
}
#else
__device__ __forceinline__ float fdot2_(f16x2 a, f16x2 b, float c) {
    return (float)a[0] * (float)b[0] + (float)a[1] * (float)b[1] + c;
}
#endif
#define PAIR(v, k) __builtin_shufflevector((v), (v), (k), (k) + 1)

// ---- fp8 e5m2: decode is EXACT (byte << 8 reinterpreted as f16) ----
#if __has_builtin(__builtin_amdgcn_perm)
__device__ __forceinline__ void decq_(unsigned int d, f16x2& a, f16x2& b) {
    a = __builtin_bit_cast(f16x2, __builtin_amdgcn_perm(d, 0u, 0x05000400u));
    b = __builtin_bit_cast(f16x2, __builtin_amdgcn_perm(d, 0u, 0x07000600u));
}
#else
__device__ __forceinline__ void decq_(unsigned int d, f16x2& a, f16x2& b) {
    a = __builtin_bit_cast(f16x2, ((d << 8) & 0x0000FF00u) | ((d << 16) & 0xFF000000u));
    b = __builtin_bit_cast(f16x2, ((d >> 8) & 0x0000FF00u) | (d & 0xFF000000u));
}
#endif

// encode float -> e5m2 byte (via f16, RNE on the 10->2 mantissa truncation)
__device__ __forceinline__ unsigned char enc5_(float w) {
    const unsigned short h = __builtin_bit_cast(unsigned short, (f16)w);
    unsigned int u = (unsigned int)h;
    u = u + 0x7Fu + ((u >> 8) & 1u);     // round-to-nearest-even on top byte
    return (unsigned char)(u >> 8);
}

// ---------------- Prologue 1: xp[t][b][j] = x[b][t][:] . W_in[j][:] + b_in[j]
__global__ __launch_bounds__(256) void k_lin_in(
    const float* __restrict__ x, const float* __restrict__ W_in,
    const float* __restrict__ b_in, float* __restrict__ xp) {
    const int tb = blockIdx.x;           // t*NB + b
    const int t = tb >> 5, b = tb & 31;
    const int tid = threadIdx.x;
    __shared__ __align__(16) float xl[NE];
    xl[tid] = x[(b * NT + t) * NE + tid];
    __syncthreads();
    const float* __restrict__ wr = W_in + tid * NE;
    float acc = b_in[tid];
#pragma unroll 8
    for (int k = 0; k < NE; k += 4)
        acc += dot4_(*(const float4*)(wr + k), *(const float4*)(xl + k));
    xp[tb * NH + tid] = acc;
}

// ---------------- Prologue 2: xw = xp.Wih^T + bih ; uax = xp.Ua^T + ub
__global__ __launch_bounds__(256) void k_proj(
    const float* __restrict__ xp, const float* __restrict__ Wih,
    const float* __restrict__ bih, const float* __restrict__ Ua,
    const float* __restrict__ ub, float* __restrict__ xw,
    float* __restrict__ uax) {
    const int tb = blockIdx.x;
    const int tid = threadIdx.x;
    __shared__ __align__(16) float xl[NH];
    xl[tid] = xp[tb * NH + tid];
    __syncthreads();
    const float* __restrict__ wr = Wih + tid * NH;
    const float* __restrict__ wz = Wih + (NH + tid) * NH;
    const float* __restrict__ wn = Wih + (2 * NH + tid) * NH;
    const float* __restrict__ wu = Ua + tid * NH;
    float ar = bih[tid], az = bih[NH + tid], an = bih[2 * NH + tid], au = ub[tid];
#pragma unroll 4
    for (int k = 0; k < NH; k += 4) {
        float4 xv = *(const float4*)(xl + k);
        ar += dot4_(*(const float4*)(wr + k), xv);
        az += dot4_(*(const float4*)(wz + k), xv);
        an += dot4_(*(const float4*)(wn + k), xv);
        au += dot4_(*(const float4*)(wu + k), xv);
    }
    float* xwp = xw + tb * (3 * NH);
    xwp[tid] = ar;
    xwp[NH + tid] = az;
    xwp[2 * NH + tid] = an;
    uax[tb * NH + tid] = au;
}

// ---------------- Pack Whh/Wa to f16x8 [kc][row] so k_attn's loads coalesce.
__global__ __launch_bounds__(256) void k_pack(
    const float* __restrict__ Whh, const float* __restrict__ Wa,
    f16x8* __restrict__ Wpk, f16x8* __restrict__ Wak) {
    const int id = blockIdx.x * 256 + threadIdx.x;
    if (id < 32 * 768) {
        const int kc = id / 768, row = id % 768;
        const float* src = Whh + row * NH + kc * 8;
        f16x8 v;
#pragma unroll
        for (int m = 0; m < 8; ++m) v[m] = (f16)src[m];
        Wpk[id] = v;
    } else {
        const int id2 = id - 32 * 768;   // < 8192
        const int kc = id2 >> 8, row = id2 & 255;
        const float* src = Wa + row * NH + kc * 8;
        f16x8 v;
#pragma unroll
        for (int m = 0; m < 8; ++m) v[m] = (f16)src[m];
        Wak[id2] = v;
    }
}

// ---------------- Pack r-gate and n-gate to e5m2 uint4 granules in k_chain's
// LDS layout: granule g = s2*1024 + tid, tid -> (j = tid>>2, c = tid&3),
// bytes = k values [c*64 + s2*16, +16) of the gate row j.
__global__ __launch_bounds__(256) void k_pack8(
    const float* __restrict__ Whh, uint4* __restrict__ wsr8,
    uint4* __restrict__ wsn8) {
    const int id = blockIdx.x * 256 + threadIdx.x;   // 0..8191
    const int gate = id >> 12;                       // 0 = r, 1 = n
    const int g = id & 4095;
    const int s2 = g >> 10, tv = g & 1023;
    const int j = tv >> 2, cc = tv & 3;
    const int row = (gate == 0) ? j : (2 * NH + j);
    const float* src = Whh + (size_t)row * NH + cc * 64 + s2 * 16;
    unsigned int w[4];
#pragma unroll
    for (int q = 0; q < 4; ++q) {
        unsigned int v = 0;
#pragma unroll
        for (int m = 0; m < 4; ++m)
            v |= (unsigned int)enc5_(src[q * 4 + m]) << (8 * m);
        w[q] = v;
    }
    (gate == 0 ? wsr8 : wsn8)[g] = uint4{w[0], w[1], w[2], w[3]};
}

// ---------------- Phase 1: sequential carried-hidden chain. 1 WG / batch.
// 1024 threads (4 waves/SIMD for latency hiding; 64-VGPR cap respected by
// design): j = tid>>2 (row), c = tid&3 (64-wide k-chunk).
// z-gate fp16 in regs (exactly 32 VGPRs); r,n gates e5m2 in LDS as uint4
// granules, lane stride 16 B (m97 pattern, conflict-free b128 reads).
// h buffer padded to 72-half chunk stride -> 4 broadcast addrs on disjoint banks.
__global__ __launch_bounds__(1024) void k_chain(
    const float* __restrict__ Whh, const float* __restrict__ bhh,
    const float* __restrict__ xw, const uint4* __restrict__ wsr8,
    const uint4* __restrict__ wsn8, float* __restrict__ Hc) {
    const int b = blockIdx.x;
    const int tid = threadIdx.x;
    const int j = tid >> 2, c = tid & 3;

    __shared__ __align__(16) uint4 Wr4[4 * 1024];    // 64 KB
    __shared__ __align__(16) uint4 Wn4[4 * 1024];    // 64 KB
    __shared__ __align__(16) f16 hb[2][4 * 72];

    // ---- stage fp8 weights (coalesced b128 copies, same layout as reads)
    for (int idx = tid; idx < 4096; idx += 1024) {
        Wr4[idx] = wsr8[idx];
        Wn4[idx] = wsn8[idx];
    }
    // ---- z-gate fp16 in regs: 32 f16x2 = 32 VGPRs
    f16x2 wz[32];
    {
        const float2* pz = (const float2*)(Whh + (size_t)(NH + j) * NH + c * 64);
#pragma unroll
        for (int m = 0; m < 32; ++m) {
            float2 v = pz[m];
            wz[m] = f16x2{(f16)v.x, (f16)v.y};
        }
    }
    const float bhr = bhh[j], bhz = bhh[NH + j], bhn = bhh[2 * NH + j];
    if (tid < NH) hb[0][(tid >> 6) * 72 + (tid & 63)] = (f16)0.f;
    float hprev = 0.f;
    int cur = 0;
    const float* __restrict__ xwB = xw + (size_t)b * 3 * NH;
    float xr = xwB[j], xz = xwB[NH + j], xn = xwB[2 * NH + j];
    __syncthreads();

#pragma unroll 1
    for (int i = 0; i < NT; ++i) {
#pragma unroll 1
        for (int t = 0; t <= i; ++t) {
            const int tn = (t < i) ? t + 1 : 0;
            const float* __restrict__ xwn = xw + (size_t)(tn * NB + b) * (3 * NH);
            const float nxr = xwn[j], nxz = xwn[NH + j], nxn = xwn[2 * NH + j];

            const f16* hc = hb[cur] + c * 72;
            float ar = 0.f, az = 0.f, an = 0.f;
#pragma unroll
            for (int s2 = 0; s2 < 4; ++s2) {
                const uint4 rq = Wr4[s2 * 1024 + tid];
                const uint4 nq = Wn4[s2 * 1024 + tid];
                const f16x8 hv0 = *(const f16x8*)(hc + s2 * 16);
                const f16x8 hv1 = *(const f16x8*)(hc + s2 * 16 + 8);
                const f16x2 p0 = PAIR(hv0, 0), p1 = PAIR(hv0, 2),
                            p2 = PAIR(hv0, 4), p3 = PAIR(hv0, 6);
                const f16x2 p4 = PAIR(hv1, 0), p5 = PAIR(hv1, 2),
                            p6 = PAIR(hv1, 4), p7 = PAIR(hv1, 6);
                az = fdot2_(wz[s2 * 8 + 0], p0, az);
                az = fdot2_(wz[s2 * 8 + 1], p1, az);
                az = fdot2_(wz[s2 * 8 + 2], p2, az);
                az = fdot2_(wz[s2 * 8 + 3], p3, az);
                az = fdot2_(wz[s2 * 8 + 4], p4, az);
                az = fdot2_(wz[s2 * 8 + 5], p5, az);
                az = fdot2_(wz[s2 * 8 + 6], p6, az);
                az = fdot2_(wz[s2 * 8 + 7], p7, az);
                f16x2 da, db;
                decq_(rq.x, da, db); ar = fdot2_(da, p0, ar); ar = fdot2_(db, p1, ar);
                decq_(rq.y, da, db); ar = fdot2_(da, p2, ar); ar = fdot2_(db, p3, ar);
                decq_(rq.z, da, db); ar = fdot2_(da, p4, ar); ar = fdot2_(db, p5, ar);
                decq_(rq.w, da, db); ar = fdot2_(da, p6, ar); ar = fdot2_(db, p7, ar);
                decq_(nq.x, da, db); an = fdot2_(da, p0, an); an = fdot2_(db, p1, an);
                decq_(nq.y, da, db); an = fdot2_(da, p2, an); an = fdot2_(db, p3, an);
                decq_(nq.z, da, db); an = fdot2_(da, p4, an); an = fdot2_(db, p5, an);
                decq_(nq.w, da, db); an = fdot2_(da, p6, an); an = fdot2_(db, p7, an);
            }
            ar += __shfl_xor(ar, 1); ar += __shfl_xor(ar, 2);
            az += __shfl_xor(az, 1); az += __shfl_xor(az, 2);
            an += __shfl_xor(an, 1); an += __shfl_xor(an, 2);
            const float r = sigmoidf_(xr + ar + bhr);
            const float z = sigmoidf_(xz + az + bhz);
            const float n = tanhf_(xn + r * (an + bhn));
            const float hnew = (1.f - z) * n + z * hprev;
            hprev = hnew;
            if (c == 0) {
                hb[cur ^ 1][(j >> 6) * 72 + (j & 63)] = (f16)hnew;
                if (t == i) Hc[((size_t)i * NB + b) * NH + j] = hnew;
            }
            xr = nxr; xz = nxz; xn = nxn;
            cur ^= 1;
            __syncthreads();
        }
    }
}

// ---------------- Phase 2: lockstep re-run of all prefix chains + fused attention.
__global__ __launch_bounds__(512) void k_attn(
    const float* __restrict__ Hc, const float* __restrict__ xw,
    const float* __restrict__ uax, const float* __restrict__ xp,
    const f16x8* __restrict__ Wpk, const f16x8* __restrict__ Wak,
    const float* __restrict__ bhh, const float* __restrict__ ba,
    const float* __restrict__ va_w, const float* __restrict__ Wo,
    const float* __restrict__ bo, float* __restrict__ out) {
    const int b  = blockIdx.x >> 3;
    const int bk = blockIdx.x & 7;
    const int tid = threadIdx.x;
    const int col = tid >> 1, c = tid & 1;
    const int lane = tid & 63, wid = tid >> 6;

    __shared__ __align__(16) float S[16][NH];
    __shared__ __align__(16) f16 Sh[16][NH];
    __shared__ float red1[8][16];
    __shared__ float mL[16], lL[16], aL[16], eL[16];
    __shared__ float redH[8][256];

    const float bhr = bhh[col], bhz = bhh[NH + col], bhn = bhh[2 * NH + col];
    const float ba_j = ba[col], va_j = va_w[col];
    float ctx[16];
#pragma unroll
    for (int u = 0; u < 16; ++u) {
        const int ic = bk + 8 * u;
        const float hv = (ic == 0) ? 0.f : Hc[((size_t)(ic - 1) * NB + b) * NH + col];
        if (c == 0) { S[u][col] = hv; Sh[u][col] = (f16)hv; }
        ctx[u] = 0.f;
    }
    if (tid < 16) { mL[tid] = -1e30f; lL[tid] = 0.f; }
    __syncthreads();

    const int imax = bk + 8 * 15;
#pragma unroll 1
    for (int t = 0; t <= imax; ++t) {
        const size_t base = (size_t)(t * NB + b);
        const float xr = xw[base * 3 * NH + col];
        const float xz = xw[base * 3 * NH + NH + col];
        const float xn = xw[base * 3 * NH + 2 * NH + col];
        const float ux = uax[base * NH + col];
        const float xpt = xp[base * NH + col];

        float ar[16], az[16], an[16];
#pragma unroll
        for (int u = 0; u < 16; ++u) { ar[u] = 0.f; az[u] = 0.f; an[u] = 0.f; }
        {
            int kc = c;
            f16x8 wR = Wpk[kc * 768 + col];
            f16x8 wZ = Wpk[kc * 768 + 256 + col];
            f16x8 wN = Wpk[kc * 768 + 512 + col];
#pragma unroll 1
            for (int kk = 0; kk < 16; ++kk) {
                const int kcn = kc + 2;
                f16x8 nR, nZ, nN;
                if (kk < 15) {
                    nR = Wpk[kcn * 768 + col];
                    nZ = Wpk[kcn * 768 + 256 + col];
                    nN = Wpk[kcn * 768 + 512 + col];
                }
#pragma unroll
                for (int u = 0; u < 16; ++u) {
                    if (bk + 8 * u < t) continue;
                    const f16x8 hv = *(const f16x8*)&Sh[u][kc * 8];
                    const f16x2 h0 = PAIR(hv, 0), h1 = PAIR(hv, 2),
                                h2 = PAIR(hv, 4), h3 = PAIR(hv, 6);
                    ar[u] = fdot2_(PAIR(wR, 0), h0, ar[u]);
                    ar[u] = fdot2_(PAIR(wR, 2), h1, ar[u]);
                    ar[u] = fdot2_(PAIR(wR, 4), h2, ar[u]);
                    ar[u] = fdot2_(PAIR(wR, 6), h3, ar[u]);
                    az[u] = fdot2_(PAIR(wZ, 0), h0, az[u]);
                    az[u] = fdot2_(PAIR(wZ, 2), h1, az[u]);
                    az[u] = fdot2_(PAIR(wZ, 4), h2, az[u]);
                    az[u] = fdot2_(PAIR(wZ, 6), h3, az[u]);
                    an[u] = fdot2_(PAIR(wN, 0), h0, an[u]);
                    an[u] = fdot2_(PAIR(wN, 2), h1, an[u]);
                    an[u] = fdot2_(PAIR(wN, 4), h2, an[u]);
                    an[u] = fdot2_(PAIR(wN, 6), h3, an[u]);
                }
                wR = nR; wZ = nZ; wN = nN; kc = kcn;
            }
        }
        float hn[16];
#pragma unroll
        for (int u = 0; u < 16; ++u) {
            if (bk + 8 * u < t) continue;
            float arf = ar[u] + __shfl_xor(ar[u], 1);
            float azf = az[u] + __shfl_xor(az[u], 1);
            float anf = an[u] + __shfl_xor(an[u], 1);
            const float r = sigmoidf_(xr + arf + bhr);
            const float z = sigmoidf_(xz + azf + bhz);
            const float n = tanhf_(xn + r * (anf + bhn));
            hn[u] = (1.f - z) * n + z * S[u][col];
        }
        __syncthreads();
#pragma unroll
        for (int u = 0; u < 16; ++u) {
            if (bk + 8 * u < t) continue;
            if (c == 0) { S[u][col] = hn[u]; Sh[u][col] = (f16)hn[u]; }
        }
        __syncthreads();

        float sc[16];
#pragma unroll
        for (int u = 0; u < 16; ++u) sc[u] = 0.f;
        {
            int kc = c;
            f16x8 wA = Wak[kc * 256 + col];
#pragma unroll 1
            for (int kk = 0; kk < 16; ++kk) {
                const int kcn = kc + 2;
                f16x8 nA;
                if (kk < 15) nA = Wak[kcn * 256 + col];
#pragma unroll
                for (int u = 0; u < 16; ++u) {
                    if (bk + 8 * u < t) continue;
                    const f16x8 hv = *(const f16x8*)&Sh[u][kc * 8];
                    sc[u] = fdot2_(PAIR(wA, 0), PAIR(hv, 0), sc[u]);
                    sc[u] = fdot2_(PAIR(wA, 2), PAIR(hv, 2), sc[u]);
                    sc[u] = fdot2_(PAIR(wA, 4), PAIR(hv, 4), sc[u]);
                    sc[u] = fdot2_(PAIR(wA, 6), PAIR(hv, 6), sc[u]);
                }
                wA = nA; kc = kcn;
            }
        }
#pragma unroll
        for (int u = 0; u < 16; ++u) {
            if (bk + 8 * u < t) continue;
            const float sv = sc[u] + __shfl_xor(sc[u], 1);
            float p = (c == 0) ? va_j * tanhf_(sv + ba_j + ux) : 0.f;
#pragma unroll
            for (int off = 32; off; off >>= 1) p += __shfl_xor(p, off);
            if (lane == 0) red1[wid][u] = p;
        }
        __syncthreads();
        if (tid < 16 && bk + 8 * tid >= t) {
            float s = 0.f;
#pragma unroll
            for (int w = 0; w < 8; ++w) s += red1[w][tid];
            const float mo = mL[tid];
            const float mn = fmaxf(mo, s);
            const float e  = __expf(s - mn);
            const float al = __expf(mo - mn);
            lL[tid] = lL[tid] * al + e;
            mL[tid] = mn; aL[tid] = al; eL[tid] = e;
        }
        __syncthreads();
#pragma unroll
        for (int u = 0; u < 16; ++u) {
            if (bk + 8 * u < t) continue;
            ctx[u] = ctx[u] * aL[u] + eL[u] * xpt;
        }
    }

#pragma unroll 1
    for (int u = 0; u < 16; ++u) {
        const float hl = S[u][col];
        const float cx = ctx[u] / lL[u];
#pragma unroll
        for (int cls = 0; cls < NC; ++cls) {
            float p = Wo[cls * (2 * NH) + col] * hl + Wo[cls * (2 * NH) + NH + col] * cx;
            p = (c == 0) ? p : 0.f;
#pragma unroll
            for (int off = 32; off; off >>= 1) p += __shfl_xor(p, off);
            if (lane == 0) redH[wid][u * 16 + cls] = p;
        }
    }
    __syncthreads();
    if (tid < 256) {
        const int u = tid >> 4, cls = tid & 15;
        const int ic = bk + 8 * u;
        float lg = bo[cls];
#pragma unroll
        for (int w = 0; w < 8; ++w) lg += redH[w][tid];
        out[((size_t)b * NT + ic) * NC + cls] = sigmoidf_(lg);
    }
}

extern "C" void kernel_launch(void* const* d_in, const int* in_sizes, int n_in,
                              void* d_out, int out_size, void* d_ws, size_t ws_size,
                              hipStream_t stream) {
    (void)in_sizes; (void)n_in; (void)out_size; (void)ws_size;
    const float* x    = (const float*)d_in[0];
    const float* W_in = (const float*)d_in[1];
    const float* b_in = (const float*)d_in[2];
    const float* Wih  = (const float*)d_in[3];
    const float* bih  = (const float*)d_in[4];
    const float* Whh  = (const float*)d_in[5];
    const float* bhh  = (const float*)d_in[6];
    const float* Wa   = (const float*)d_in[7];
    const float* ba   = (const float*)d_in[8];
    const float* Ua   = (const float*)d_in[9];
    const float* ub   = (const float*)d_in[10];
    const float* va_w = (const float*)d_in[11];
    // d_in[12] = va_b: cancels in softmax
    const float* Wo   = (const float*)d_in[13];
    const float* bo   = (const float*)d_in[14];
    float* out = (float*)d_out;

    float* ws  = (float*)d_ws;
    float* xp  = ws;                                    // NT*NB*NH        (4 MB)
    float* xw  = xp  + (size_t)NT * NB * NH;            // NT*NB*3NH       (12.6 MB)
    float* uax = xw  + (size_t)NT * NB * 3 * NH;        // NT*NB*NH        (4 MB)
    float* Hc  = uax + (size_t)NT * NB * NH;            // NT*NB*NH        (4 MB)
    f16x8* Wpk = (f16x8*)(Hc + (size_t)NT * NB * NH);   // 32*768 f16x8    (384 KB)
    f16x8* Wak = Wpk + 32 * 768;                        // 32*256 f16x8    (128 KB)
    uint4* wsr8 = (uint4*)(Wak + 32 * 256);             // 4096 uint4      (64 KB)
    uint4* wsn8 = wsr8 + 4096;                          // 4096 uint4      (64 KB)

    hipLaunchKernelGGL(k_lin_in, dim3(NT * NB), dim3(256), 0, stream, x, W_in, b_in, xp);
    hipLaunchKernelGGL(k_proj,   dim3(NT * NB), dim3(256), 0, stream, xp, Wih, bih, Ua, ub, xw, uax);
    hipLaunchKernelGGL(k_pack,   dim3(128),     dim3(256), 0, stream, Whh, Wa, Wpk, Wak);
    hipLaunchKernelGGL(k_pack8,  dim3(32),      dim3(256), 0, stream, Whh, wsr8, wsn8);
    hipLaunchKernelGGL(k_chain,  dim3(NB),      dim3(1024), 0, stream, Whh, bhh, xw, wsr8, wsn8, Hc);
    hipLaunchKernelGGL(k_attn,   dim3(NB * 8),  dim3(512), 0, stream,
                       Hc, xw, uax, xp, Wpk, Wak, bhh, ba, va_w, Wo, bo, out);
}